// Round 6
// baseline (486.482 us; speedup 1.0000x reference)
//
#include <hip/hip_runtime.h>

#define DIMV 1024
#define NHV  16
#define HDV  64
#define BV   8
#define LQV  512
#define LKV  1024
#define PSTR 1032   // sP row stride in bf16: 2064B/row -> 2-way banks max (free)

typedef __bf16 bfrag  __attribute__((ext_vector_type(8)));
typedef float  f32x4  __attribute__((ext_vector_type(4)));
typedef unsigned short u16;
typedef unsigned int   u32;
typedef unsigned long long u64;

typedef const __attribute__((address_space(1))) u32 gu32;
typedef __attribute__((address_space(3))) u32 lu32;

__device__ __forceinline__ u16 f2bf(float f) {
    u32 x = __builtin_bit_cast(u32, f);
    x = x + 0x7FFFu + ((x >> 16) & 1u);   // RNE
    return (u16)(x >> 16);
}

// async global->LDS, 16B per lane; LDS dest must be wave-uniform base (+lane*16 implicit)
__device__ __forceinline__ void g2l16(const u16* g, const u16* l) {
    __builtin_amdgcn_global_load_lds(
        reinterpret_cast<gu32*>(reinterpret_cast<u64>(g)),
        reinterpret_cast<lu32*>((u32)reinterpret_cast<u64>(l)),
        16, 0, 0);
}

// fp32 -> bf16 (RNE), float4-vectorized
__global__ __launch_bounds__(256)
void cast_bf(const float* __restrict__ src, u16* __restrict__ dst, int n4)
{
    const int i = blockIdx.x * 256 + threadIdx.x;
    if (i < n4) {
        const float4 v = reinterpret_cast<const float4*>(src)[i];
        ushort4 o;
        o.x = f2bf(v.x); o.y = f2bf(v.y); o.z = f2bf(v.z); o.w = f2bf(v.w);
        reinterpret_cast<ushort4*>(dst)[i] = o;
    }
}

// C[M,N] = A[M,K] @ W[N,K]^T + bias(fp32), K=N=1024, bf16 in, fp32 accum.
// m97-style: 128x128 block tile, BK=64, global_load_lds staging, 4 waves 2x2, 4x4 acc.
// MODE 0: bf16 row-major; MODE 1: bf16 V^T per b; MODE 2: fp32 + residual
template<int MODE>
__global__ __launch_bounds__(256)
void gemm_nt(const u16* __restrict__ A, const u16* __restrict__ W,
             const float* __restrict__ bias, void* __restrict__ Cout,
             const float* __restrict__ resid)
{
    __shared__ __align__(16) u16 sA[128 * 64];
    __shared__ __align__(16) u16 sB[128 * 64];

    const int t    = threadIdx.x;
    const int lane = t & 63;
    const int w    = t >> 6;
    const int quad = lane >> 4;
    const int r    = lane & 15;
    const int wr   = (w >> 1) * 64;   // wave row offset in tile
    const int wc   = (w & 1) * 64;    // wave col offset
    const int mb   = blockIdx.x * 128;
    const int nb   = blockIdx.y * 128;

    const int srow  = lane >> 3;        // 0..7 row within 8-row chunk
    const int skoff = (lane & 7) * 8;   // k element offset

    f32x4 acc[4][4] = {};

    const u16* Abase = A + (size_t)mb * 1024 + skoff;
    const u16* Wbase = W + (size_t)nb * 1024 + skoff;

    for (int k0 = 0; k0 < 1024; k0 += 64) {
        // stage A/B tiles (128x64 each): wave w stages chunks w*4..w*4+3 (8 rows each)
#pragma unroll
        for (int it = 0; it < 4; ++it) {
            const int c = w * 4 + it;
            const int row = c * 8 + srow;
            g2l16(Abase + (size_t)row * 1024 + k0, sA + c * 512);
            g2l16(Wbase + (size_t)row * 1024 + k0, sB + c * 512);
        }
        __syncthreads();   // drains vmcnt (async LDS loads) + barrier
#pragma unroll
        for (int kk = 0; kk < 2; ++kk) {
            bfrag af[4], bg[4];
#pragma unroll
            for (int i = 0; i < 4; ++i)
                af[i] = *reinterpret_cast<const bfrag*>(sA + (wr + i * 16 + r) * 64 + kk * 32 + quad * 8);
#pragma unroll
            for (int j = 0; j < 4; ++j)
                bg[j] = *reinterpret_cast<const bfrag*>(sB + (wc + j * 16 + r) * 64 + kk * 32 + quad * 8);
#pragma unroll
            for (int i = 0; i < 4; ++i)
#pragma unroll
                for (int j = 0; j < 4; ++j)
                    acc[i][j] = __builtin_amdgcn_mfma_f32_16x16x32_bf16(af[i], bg[j], acc[i][j], 0, 0, 0);
        }
        __syncthreads();   // all reads done before restage
    }

#pragma unroll
    for (int i = 0; i < 4; i++)
#pragma unroll
    for (int j = 0; j < 4; j++) {
        const int colg = nb + wc + j * 16 + r;
        const float bv = bias[colg];
#pragma unroll
        for (int reg = 0; reg < 4; reg++) {
            const int rowg = mb + wr + i * 16 + quad * 4 + reg;
            const float v = acc[i][j][reg] + bv;
            if (MODE == 0) {
                ((u16*)Cout)[(size_t)rowg * 1024 + colg] = f2bf(v);
            } else if (MODE == 1) {
                ((u16*)Cout)[((size_t)((rowg >> 10) << 10) + colg) * 1024 + (rowg & 1023)] = f2bf(v);
            } else {
                ((float*)Cout)[(size_t)rowg * 1024 + colg] = v + resid[(size_t)rowg * 1024 + colg];
            }
        }
    }
}

// softmax phase on in-reg scores: scale, wave-local max (over 16 lanes of quad),
// exp(s-m), wave-local sum. Pure reg/shuffle — no LDS.
__device__ __forceinline__ void sm_reduce(f32x4 (&s)[16], float (&mw)[4], float (&sw)[4])
{
    const float scale = 0.125f;   // 1/sqrt(64)
#pragma unroll
    for (int reg = 0; reg < 4; ++reg) mw[reg] = -1e30f;
#pragma unroll
    for (int i = 0; i < 16; ++i)
#pragma unroll
        for (int reg = 0; reg < 4; ++reg) {
            s[i][reg] *= scale;
            mw[reg] = fmaxf(mw[reg], s[i][reg]);
        }
#pragma unroll
    for (int reg = 0; reg < 4; ++reg)
#pragma unroll
        for (int off = 1; off < 16; off <<= 1)
            mw[reg] = fmaxf(mw[reg], __shfl_xor(mw[reg], off));
#pragma unroll
    for (int reg = 0; reg < 4; ++reg) sw[reg] = 0.f;
#pragma unroll
    for (int i = 0; i < 16; ++i)
#pragma unroll
        for (int reg = 0; reg < 4; ++reg) {
            s[i][reg] = __expf(s[i][reg] - mw[reg]);
            sw[reg] += s[i][reg];
        }
#pragma unroll
    for (int reg = 0; reg < 4; ++reg)
#pragma unroll
        for (int off = 1; off < 16; off <<= 1)
            sw[reg] += __shfl_xor(sw[reg], off);
}

// Attention v8: v7 pipeline + occupancy restored.
// Round-5 lesson: v7's 256 blocks == CU count -> 1 wave/SIMD (Occ 11.5%),
// pure latency-bound (MfmaUtil 3.3%, VALU 15%, HBM 2.8%). v4 proved
// 2 waves/SIMD is worth more than structure. Fix: split 16 heads across
// 2 blocks -> grid (8,32,2)=512 blocks; at 212 VGPR two 256-thr blocks
// co-reside per CU (2 waves/SIMD, 8 waves/CU). Head-split keeps Q/K/V
// reads disjoint (d-slices), preserving the L2 affinity win (FETCH 20.6MB).
// attnw: 2-way combine via memset + atomicAdd (measured cheap in v3).
__global__ __launch_bounds__(256, 2)
void attn_kernel(const u16* __restrict__ q, const u16* __restrict__ k,
                 const u16* __restrict__ vT, u16* __restrict__ ctx,
                 float* __restrict__ attnw)
{
    __shared__ __align__(16) u16 sP[16 * PSTR];   // 33024 B
    __shared__ float redm[64];
    __shared__ float reds[64];

    const int t    = threadIdx.x;     // 0..255
    const int lane = t & 63;
    const int w    = t >> 6;          // wave 0..3
    const int quad = lane >> 4;       // 0..3
    const int r    = lane & 15;
    const int b    = blockIdx.x;      // batch -> XCD affinity (grid.x == 8)
    const int q0   = blockIdx.y * 16;
    const int hg   = blockIdx.z;      // head-group 0/1 (8 heads each)

    const int row16 = quad * 4;

    f32x4 wacc[16] = {};
    f32x4 s[16];
    float mw[4], sw[4];

    // ---- prologue: QK for head hg*8 + softmax phase (not overlapped) ----
    {
        const int dbase = (hg * 8) * HDV + quad * 8;
        const u16* qp = q + (size_t)(b * LQV + q0 + r) * DIMV + dbase;
        const bfrag qa0 = *reinterpret_cast<const bfrag*>(qp);
        const bfrag qa1 = *reinterpret_cast<const bfrag*>(qp + 32);
#pragma unroll
        for (int u = 0; u < 16; ++u) {
            const u16* kp = k + (size_t)(b * LKV + w * 256 + u * 16 + r) * DIMV + dbase;
            const bfrag kb0 = *reinterpret_cast<const bfrag*>(kp);
            const bfrag kb1 = *reinterpret_cast<const bfrag*>(kp + 32);
            f32x4 a = {};
            a    = __builtin_amdgcn_mfma_f32_16x16x32_bf16(qa0, kb0, a, 0, 0, 0);
            s[u] = __builtin_amdgcn_mfma_f32_16x16x32_bf16(qa1, kb1, a, 0, 0, 0);
        }
        sm_reduce(s, mw, sw);
    }

    for (int hh = 0; hh < 8; ++hh) {
        const int h = hg * 8 + hh;

        if (r == 0) {
#pragma unroll
            for (int reg = 0; reg < 4; ++reg) {
                redm[w * 16 + row16 + reg] = mw[reg];
                reds[w * 16 + row16 + reg] = sw[reg];
            }
        }
        __syncthreads();   // bar A: redm/reds ready; also: all PV(h-1) sP reads done

        // ---- flash combine: factor = exp(m_w - M) / total ----
        float factor[4];
#pragma unroll
        for (int reg = 0; reg < 4; ++reg) {
            const int rr = row16 + reg;
            const float m0 = redm[rr], m1 = redm[16 + rr], m2 = redm[32 + rr], m3 = redm[48 + rr];
            const float M = fmaxf(fmaxf(m0, m1), fmaxf(m2, m3));
            const float total = __expf(m0 - M) * reds[rr]      + __expf(m1 - M) * reds[16 + rr] +
                                __expf(m2 - M) * reds[32 + rr] + __expf(m3 - M) * reds[48 + rr];
            factor[reg] = __expf(mw[reg] - M) / total;
        }

        // ---- normalize, accumulate mean-prob, write bf16 P to LDS ----
#pragma unroll
        for (int i = 0; i < 16; ++i)
#pragma unroll
            for (int reg = 0; reg < 4; ++reg) {
                const float pn = s[i][reg] * factor[reg];
                wacc[i][reg] += pn;
                sP[(row16 + reg) * PSTR + w * 256 + i * 16 + r] = f2bf(pn);
            }
        __syncthreads();   // bar B: sP(h) ready for PV

        // ---- overlap region: PV(h) interleaved with QK(h+1) ----
        const int n0 = w * 16;
        const u16* vb = vT + (size_t)(b * DIMV + h * HDV + n0 + r) * LKV;
        f32x4 c0 = {}, c1 = {}, c2 = {}, c3 = {};

        if (hh < 7) {
            const int dbase2 = (h + 1) * HDV + quad * 8;
            const u16* qp2 = q + (size_t)(b * LQV + q0 + r) * DIMV + dbase2;
            const bfrag qa0 = *reinterpret_cast<const bfrag*>(qp2);
            const bfrag qa1 = *reinterpret_cast<const bfrag*>(qp2 + 32);
#pragma unroll
            for (int u = 0; u < 16; ++u) {
                // QK iter u for head h+1 (global K + MFMA, s[] regs are dead -> reuse)
                const u16* kp = k + (size_t)(b * LKV + w * 256 + u * 16 + r) * DIMV + dbase2;
                const bfrag kb0 = *reinterpret_cast<const bfrag*>(kp);
                const bfrag kb1 = *reinterpret_cast<const bfrag*>(kp + 32);
                f32x4 a = {};
                a    = __builtin_amdgcn_mfma_f32_16x16x32_bf16(qa0, kb0, a, 0, 0, 0);
                s[u] = __builtin_amdgcn_mfma_f32_16x16x32_bf16(qa1, kb1, a, 0, 0, 0);
                // PV iter u (first 8): LDS P + global V, 4 independent chains
                if (u < 8) {
                    const int kk = u * 128;
                    const bfrag a0 = *reinterpret_cast<const bfrag*>(&sP[r * PSTR + kk      + quad * 8]);
                    const bfrag a1 = *reinterpret_cast<const bfrag*>(&sP[r * PSTR + kk + 32 + quad * 8]);
                    const bfrag a2 = *reinterpret_cast<const bfrag*>(&sP[r * PSTR + kk + 64 + quad * 8]);
                    const bfrag a3 = *reinterpret_cast<const bfrag*>(&sP[r * PSTR + kk + 96 + quad * 8]);
                    const bfrag b0 = *reinterpret_cast<const bfrag*>(vb + kk      + quad * 8);
                    const bfrag b1 = *reinterpret_cast<const bfrag*>(vb + kk + 32 + quad * 8);
                    const bfrag b2 = *reinterpret_cast<const bfrag*>(vb + kk + 64 + quad * 8);
                    const bfrag b3 = *reinterpret_cast<const bfrag*>(vb + kk + 96 + quad * 8);
                    c0 = __builtin_amdgcn_mfma_f32_16x16x32_bf16(a0, b0, c0, 0, 0, 0);
                    c1 = __builtin_amdgcn_mfma_f32_16x16x32_bf16(a1, b1, c1, 0, 0, 0);
                    c2 = __builtin_amdgcn_mfma_f32_16x16x32_bf16(a2, b2, c2, 0, 0, 0);
                    c3 = __builtin_amdgcn_mfma_f32_16x16x32_bf16(a3, b3, c3, 0, 0, 0);
                }
            }
            sm_reduce(s, mw, sw);   // softmax phase for head h+1 (reg/shuffle only)
        } else {
            // last head: PV only
#pragma unroll
            for (int u = 0; u < 8; ++u) {
                const int kk = u * 128;
                const bfrag a0 = *reinterpret_cast<const bfrag*>(&sP[r * PSTR + kk      + quad * 8]);
                const bfrag a1 = *reinterpret_cast<const bfrag*>(&sP[r * PSTR + kk + 32 + quad * 8]);
                const bfrag a2 = *reinterpret_cast<const bfrag*>(&sP[r * PSTR + kk + 64 + quad * 8]);
                const bfrag a3 = *reinterpret_cast<const bfrag*>(&sP[r * PSTR + kk + 96 + quad * 8]);
                const bfrag b0 = *reinterpret_cast<const bfrag*>(vb + kk      + quad * 8);
                const bfrag b1 = *reinterpret_cast<const bfrag*>(vb + kk + 32 + quad * 8);
                const bfrag b2 = *reinterpret_cast<const bfrag*>(vb + kk + 64 + quad * 8);
                const bfrag b3 = *reinterpret_cast<const bfrag*>(vb + kk + 96 + quad * 8);
                c0 = __builtin_amdgcn_mfma_f32_16x16x32_bf16(a0, b0, c0, 0, 0, 0);
                c1 = __builtin_amdgcn_mfma_f32_16x16x32_bf16(a1, b1, c1, 0, 0, 0);
                c2 = __builtin_amdgcn_mfma_f32_16x16x32_bf16(a2, b2, c2, 0, 0, 0);
                c3 = __builtin_amdgcn_mfma_f32_16x16x32_bf16(a3, b3, c3, 0, 0, 0);
            }
        }

        const f32x4 c = (c0 + c1) + (c2 + c3);
#pragma unroll
        for (int reg = 0; reg < 4; ++reg)
            ctx[(size_t)(b * LQV + q0 + row16 + reg) * DIMV + h * HDV + n0 + r] = f2bf(c[reg]);
    }

    // ---- attn_weights mean: this block's 8-head sum; 2-way atomic combine ----
    const float inv16 = 1.0f / 16.0f;
#pragma unroll
    for (int i = 0; i < 16; ++i)
#pragma unroll
        for (int reg = 0; reg < 4; ++reg)
            atomicAdd(&attnw[(size_t)(b * LQV + q0 + row16 + reg) * LKV + w * 256 + i * 16 + r],
                      wacc[i][reg] * inv16);
}

// LayerNorm per row of 1024; x fp32 (attended+residual), g/b fp32, out fp32
__global__ __launch_bounds__(256)
void ln_kernel(const float* __restrict__ x, const float* __restrict__ g,
               const float* __restrict__ bta, float* __restrict__ out)
{
    __shared__ float red[8];
    const int row = blockIdx.x;
    const int t = threadIdx.x;
    const int w = t >> 6;
    const float4 xv = reinterpret_cast<const float4*>(x + (size_t)row * DIMV)[t];

    float s = xv.x + xv.y + xv.z + xv.w;
#pragma unroll
    for (int off = 32; off; off >>= 1) s += __shfl_down(s, off);
    if ((t & 63) == 0) red[w] = s;
    __syncthreads();
    const float mu = (red[0] + red[1] + red[2] + red[3]) * (1.0f / 1024.0f);

    const float d0 = xv.x - mu, d1 = xv.y - mu, d2 = xv.z - mu, d3 = xv.w - mu;
    float s2 = d0 * d0 + d1 * d1 + d2 * d2 + d3 * d3;
#pragma unroll
    for (int off = 32; off; off >>= 1) s2 += __shfl_down(s2, off);
    if ((t & 63) == 0) red[4 + w] = s2;
    __syncthreads();
    const float var = (red[4] + red[5] + red[6] + red[7]) * (1.0f / 1024.0f);
    const float inv = rsqrtf(var + 1e-5f);

    float4 o;
    const int c = t * 4;
    o.x = d0 * inv * g[c + 0] + bta[c + 0];
    o.y = d1 * inv * g[c + 1] + bta[c + 1];
    o.z = d2 * inv * g[c + 2] + bta[c + 2];
    o.w = d3 * inv * g[c + 3] + bta[c + 3];
    reinterpret_cast<float4*>(out + (size_t)row * DIMV)[t] = o;
}

extern "C" void kernel_launch(void* const* d_in, const int* in_sizes, int n_in,
                              void* d_out, int out_size, void* d_ws, size_t ws_size,
                              hipStream_t stream)
{
    const float* text = (const float*)d_in[0];   // (8,512,1024)
    const float* vis  = (const float*)d_in[1];   // (8,1024,1024)
    const float* wqkv = (const float*)d_in[2];   // (3072,1024)
    const float* bqkv = (const float*)d_in[3];   // (3072,)
    const float* outw = (const float*)d_in[4];   // (1024,1024)
    const float* outb = (const float*)d_in[5];   // (1024,)
    const float* lng  = (const float*)d_in[6];   // (1024,)
    const float* lnb  = (const float*)d_in[7];   // (1024,)

    // Workspace: exactly 64 MiB via liveness overlays (as in passing rounds 5/6).
    char* ws = (char*)d_ws;
    u16*   vis_bf  = (u16*)(ws);                          // 0-16M
    u16*   ctxb    = (u16*)(ws);                          // 0-8M   (st4 w; st5 r)
    u16*   wqkv_bf = (u16*)(ws + (size_t)(16u << 20));    // 16-22M
    u16*   outw_bf = (u16*)(ws + (size_t)(22u << 20));    // 22-24M
    u16*   qb      = (u16*)(ws + (size_t)(24u << 20));    // 24-32M
    u16*   text_bf = (u16*)(ws + (size_t)(32u << 20));    // 32-40M (dead after st1)
    u16*   kb      = (u16*)(ws + (size_t)(32u << 20));    // 32-48M
    float* attb    = (float*)(ws + (size_t)(32u << 20));  // 32-48M (st5 w; st6 r)
    u16*   vTb     = (u16*)(ws + (size_t)(48u << 20));    // 48-64M

    float* outp  = (float*)d_out;                 // fp32 outputs, concat (out, attn_weights)
    float* attnw = outp + (size_t)4096 * 1024;

    const dim3 blk(256);
    // stage 0: fp32 -> bf16 casts
    cast_bf<<<dim3(8192), blk, 0, stream>>>(vis,  vis_bf,  8388608 / 4);
    cast_bf<<<dim3(3072), blk, 0, stream>>>(wqkv, wqkv_bf, 3145728 / 4);
    cast_bf<<<dim3(1024), blk, 0, stream>>>(outw, outw_bf, 1048576 / 4);
    cast_bf<<<dim3(4096), blk, 0, stream>>>(text, text_bf, 4194304 / 4);

    // stage 1: Q = text @ Wq^T + bq   (M=4096 -> 32x8 blocks)
    gemm_nt<0><<<dim3(32, 8), blk, 0, stream>>>(text_bf, wqkv_bf, bqkv, qb, nullptr);
    // stage 2: K = vision @ Wk^T + bk (M=8192 -> 64x8; overwrites text_bf)
    gemm_nt<0><<<dim3(64, 8), blk, 0, stream>>>(vis_bf, wqkv_bf + DIMV * DIMV, bqkv + DIMV, kb, nullptr);
    // stage 3: V^T = (vision @ Wv^T + bv) transposed per b
    gemm_nt<1><<<dim3(64, 8), blk, 0, stream>>>(vis_bf, wqkv_bf + 2 * DIMV * DIMV, bqkv + 2 * DIMV, vTb, nullptr);
    // stage 4: attention; head-split x2 for 2 blocks/CU; b-major grid for XCD L2 affinity
    hipMemsetAsync(attnw, 0, (size_t)4096 * 1024 * sizeof(float), stream);
    attn_kernel<<<dim3(8, 32, 2), dim3(256), 0, stream>>>(qb, kb, vTb, ctxb, attnw);
    // stage 5: attended = ctx @ out_w^T + out_b + text (fp32), over dead kb
    gemm_nt<2><<<dim3(32, 8), blk, 0, stream>>>(ctxb, outw_bf, outb, attb, text);
    // stage 6: layernorm -> out (fp32)
    ln_kernel<<<dim3(4096), blk, 0, stream>>>(attb, lng, lnb, outp);
}

// Round 7
// 454.040 us; speedup vs baseline: 1.0715x; 1.0715x over previous
//
#include <hip/hip_runtime.h>

#define DIMV 1024
#define NHV  16
#define HDV  64
#define BV   8
#define LQV  512
#define LKV  1024
#define PSTR 1032   // sP row stride in bf16: 2064B/row -> 2-way banks max (free)

typedef __bf16 bfrag  __attribute__((ext_vector_type(8)));
typedef float  f32x4  __attribute__((ext_vector_type(4)));
typedef unsigned short u16;
typedef unsigned int   u32;
typedef unsigned long long u64;

typedef const __attribute__((address_space(1))) u32 gu32;
typedef __attribute__((address_space(3))) u32 lu32;

__device__ __forceinline__ u16 f2bf(float f) {
    u32 x = __builtin_bit_cast(u32, f);
    x = x + 0x7FFFu + ((x >> 16) & 1u);   // RNE
    return (u16)(x >> 16);
}

// async global->LDS, 16B per lane; LDS dest must be wave-uniform base (+lane*16 implicit)
__device__ __forceinline__ void g2l16(const u16* g, const u16* l) {
    __builtin_amdgcn_global_load_lds(
        reinterpret_cast<gu32*>(reinterpret_cast<u64>(g)),
        reinterpret_cast<lu32*>((u32)reinterpret_cast<u64>(l)),
        16, 0, 0);
}

// All four fp32->bf16 casts in ONE dispatch (ranges exact multiples, no bounds checks)
__global__ __launch_bounds__(256)
void cast_all(const float* __restrict__ vis,  const float* __restrict__ wqkv,
              const float* __restrict__ outw, const float* __restrict__ text,
              u16* __restrict__ vis_bf, u16* __restrict__ wqkv_bf,
              u16* __restrict__ outw_bf, u16* __restrict__ text_bf)
{
    const int bx = blockIdx.x;
    const float* src; u16* dst; int i;
    if (bx < 8192)       { src = vis;  dst = vis_bf;  i = bx * 256 + threadIdx.x; }
    else if (bx < 11264) { src = wqkv; dst = wqkv_bf; i = (bx - 8192) * 256 + threadIdx.x; }
    else if (bx < 12288) { src = outw; dst = outw_bf; i = (bx - 11264) * 256 + threadIdx.x; }
    else                 { src = text; dst = text_bf; i = (bx - 12288) * 256 + threadIdx.x; }
    const float4 v = reinterpret_cast<const float4*>(src)[i];
    ushort4 o;
    o.x = f2bf(v.x); o.y = f2bf(v.y); o.z = f2bf(v.z); o.w = f2bf(v.w);
    reinterpret_cast<ushort4*>(dst)[i] = o;
}

// Q+K+V projections in ONE dispatch: grid.x = 32(Q) + 64(K) + 64(V^T) row-tiles,
// grid.y = 8 col-tiles. 1280 blocks -> ~5 blocks/CU vs 3 serialized underfilled
// launches. Body identical to m97-style gemm_nt; per-block uniform operand select.
__global__ __launch_bounds__(256)
void qkv_gemm(const u16* __restrict__ text_bf, const u16* __restrict__ vis_bf,
              const u16* __restrict__ wqkv_bf, const float* __restrict__ bqkv,
              u16* __restrict__ qb, u16* __restrict__ kb, u16* __restrict__ vTb)
{
    __shared__ __align__(16) u16 sA[128 * 64];
    __shared__ __align__(16) u16 sB[128 * 64];

    const int bx = blockIdx.x;
    const u16* A; const u16* W; const float* bias; u16* C; int mb, vmode;
    if (bx < 32)      { A = text_bf; W = wqkv_bf;               bias = bqkv;        C = qb;  mb = bx * 128;        vmode = 0; }
    else if (bx < 96) { A = vis_bf;  W = wqkv_bf + 1024 * 1024; bias = bqkv + 1024; C = kb;  mb = (bx - 32) * 128; vmode = 0; }
    else              { A = vis_bf;  W = wqkv_bf + 2097152;     bias = bqkv + 2048; C = vTb; mb = (bx - 96) * 128; vmode = 1; }

    const int t    = threadIdx.x;
    const int lane = t & 63;
    const int w    = t >> 6;
    const int quad = lane >> 4;
    const int r    = lane & 15;
    const int wr   = (w >> 1) * 64;
    const int wc   = (w & 1) * 64;
    const int nb   = blockIdx.y * 128;

    const int srow  = lane >> 3;
    const int skoff = (lane & 7) * 8;

    f32x4 acc[4][4] = {};

    const u16* Abase = A + (size_t)mb * 1024 + skoff;
    const u16* Wbase = W + (size_t)nb * 1024 + skoff;

    for (int k0 = 0; k0 < 1024; k0 += 64) {
#pragma unroll
        for (int it = 0; it < 4; ++it) {
            const int c = w * 4 + it;
            const int row = c * 8 + srow;
            g2l16(Abase + (size_t)row * 1024 + k0, sA + c * 512);
            g2l16(Wbase + (size_t)row * 1024 + k0, sB + c * 512);
        }
        __syncthreads();
#pragma unroll
        for (int kk = 0; kk < 2; ++kk) {
            bfrag af[4], bg[4];
#pragma unroll
            for (int i = 0; i < 4; ++i)
                af[i] = *reinterpret_cast<const bfrag*>(sA + (wr + i * 16 + r) * 64 + kk * 32 + quad * 8);
#pragma unroll
            for (int j = 0; j < 4; ++j)
                bg[j] = *reinterpret_cast<const bfrag*>(sB + (wc + j * 16 + r) * 64 + kk * 32 + quad * 8);
#pragma unroll
            for (int i = 0; i < 4; ++i)
#pragma unroll
                for (int j = 0; j < 4; ++j)
                    acc[i][j] = __builtin_amdgcn_mfma_f32_16x16x32_bf16(af[i], bg[j], acc[i][j], 0, 0, 0);
        }
        __syncthreads();
    }

#pragma unroll
    for (int i = 0; i < 4; i++)
#pragma unroll
    for (int j = 0; j < 4; j++) {
        const int colg = nb + wc + j * 16 + r;
        const float bv = bias[colg];
#pragma unroll
        for (int reg = 0; reg < 4; reg++) {
            const int rowg = mb + wr + i * 16 + quad * 4 + reg;
            const float v = acc[i][j][reg] + bv;
            if (vmode == 0) {
                C[(size_t)rowg * 1024 + colg] = f2bf(v);
            } else {
                C[((size_t)((rowg >> 10) << 10) + colg) * 1024 + (rowg & 1023)] = f2bf(v);
            }
        }
    }
}

// Stage-5 GEMM: attended = ctx @ out_w^T + out_b + text (fp32 out with residual)
__global__ __launch_bounds__(256)
void gemm_out(const u16* __restrict__ A, const u16* __restrict__ W,
              const float* __restrict__ bias, float* __restrict__ Cout,
              const float* __restrict__ resid)
{
    __shared__ __align__(16) u16 sA[128 * 64];
    __shared__ __align__(16) u16 sB[128 * 64];

    const int t    = threadIdx.x;
    const int lane = t & 63;
    const int w    = t >> 6;
    const int quad = lane >> 4;
    const int r    = lane & 15;
    const int wr   = (w >> 1) * 64;
    const int wc   = (w & 1) * 64;
    const int mb   = blockIdx.x * 128;
    const int nb   = blockIdx.y * 128;

    const int srow  = lane >> 3;
    const int skoff = (lane & 7) * 8;

    f32x4 acc[4][4] = {};

    const u16* Abase = A + (size_t)mb * 1024 + skoff;
    const u16* Wbase = W + (size_t)nb * 1024 + skoff;

    for (int k0 = 0; k0 < 1024; k0 += 64) {
#pragma unroll
        for (int it = 0; it < 4; ++it) {
            const int c = w * 4 + it;
            const int row = c * 8 + srow;
            g2l16(Abase + (size_t)row * 1024 + k0, sA + c * 512);
            g2l16(Wbase + (size_t)row * 1024 + k0, sB + c * 512);
        }
        __syncthreads();
#pragma unroll
        for (int kk = 0; kk < 2; ++kk) {
            bfrag af[4], bg[4];
#pragma unroll
            for (int i = 0; i < 4; ++i)
                af[i] = *reinterpret_cast<const bfrag*>(sA + (wr + i * 16 + r) * 64 + kk * 32 + quad * 8);
#pragma unroll
            for (int j = 0; j < 4; ++j)
                bg[j] = *reinterpret_cast<const bfrag*>(sB + (wc + j * 16 + r) * 64 + kk * 32 + quad * 8);
#pragma unroll
            for (int i = 0; i < 4; ++i)
#pragma unroll
                for (int j = 0; j < 4; ++j)
                    acc[i][j] = __builtin_amdgcn_mfma_f32_16x16x32_bf16(af[i], bg[j], acc[i][j], 0, 0, 0);
        }
        __syncthreads();
    }

#pragma unroll
    for (int i = 0; i < 4; i++)
#pragma unroll
    for (int j = 0; j < 4; j++) {
        const int colg = nb + wc + j * 16 + r;
        const float bv = bias[colg];
#pragma unroll
        for (int reg = 0; reg < 4; reg++) {
            const int rowg = mb + wr + i * 16 + quad * 4 + reg;
            const float v = acc[i][j][reg] + bv;
            Cout[(size_t)rowg * 1024 + colg] = v + resid[(size_t)rowg * 1024 + colg];
        }
    }
}

// softmax phase on in-reg scores: scale, wave-local max (over 16 lanes of quad),
// exp(s-m), wave-local sum. Pure reg/shuffle — no LDS.
__device__ __forceinline__ void sm_reduce(f32x4 (&s)[16], float (&mw)[4], float (&sw)[4])
{
    const float scale = 0.125f;   // 1/sqrt(64)
#pragma unroll
    for (int reg = 0; reg < 4; ++reg) mw[reg] = -1e30f;
#pragma unroll
    for (int i = 0; i < 16; ++i)
#pragma unroll
        for (int reg = 0; reg < 4; ++reg) {
            s[i][reg] *= scale;
            mw[reg] = fmaxf(mw[reg], s[i][reg]);
        }
#pragma unroll
    for (int reg = 0; reg < 4; ++reg)
#pragma unroll
        for (int off = 1; off < 16; off <<= 1)
            mw[reg] = fmaxf(mw[reg], __shfl_xor(mw[reg], off));
#pragma unroll
    for (int reg = 0; reg < 4; ++reg) sw[reg] = 0.f;
#pragma unroll
    for (int i = 0; i < 16; ++i)
#pragma unroll
        for (int reg = 0; reg < 4; ++reg) {
            s[i][reg] = __expf(s[i][reg] - mw[reg]);
            sw[reg] += s[i][reg];
        }
#pragma unroll
    for (int reg = 0; reg < 4; ++reg)
#pragma unroll
        for (int off = 1; off < 16; off <<= 1)
            sw[reg] += __shfl_xor(sw[reg], off);
}

// Attention v9: v8 grid (2 blocks/CU) WITHOUT the compile-time register cap.
// Round-6 lesson: any launch_bounds multi-wave/EU request pins arch VGPR<=128
// -> pipeline (~212 live regs) spills (282MB writes). Round-5 lesson: at 212
// VGPR, runtime co-residency of 2 blocks/CU is still legal (2x212=424<=512/SIMD)
// — occupancy there was grid-limited, not VGPR-limited. So: 512 blocks
// (8 heads each), compile at (256,1) -> 212 regs, zero spills, HW gives
// 2 waves/SIMD. b-major grid.x keeps the XCD L2 affinity (FETCH 20.6MB in r5).
__global__ __launch_bounds__(256, 1)
void attn_kernel(const u16* __restrict__ q, const u16* __restrict__ k,
                 const u16* __restrict__ vT, u16* __restrict__ ctx,
                 float* __restrict__ attnw)
{
    __shared__ __align__(16) u16 sP[16 * PSTR];   // 33024 B
    __shared__ float redm[64];
    __shared__ float reds[64];

    const int t    = threadIdx.x;     // 0..255
    const int lane = t & 63;
    const int w    = t >> 6;          // wave 0..3
    const int quad = lane >> 4;       // 0..3
    const int r    = lane & 15;
    const int b    = blockIdx.x;      // batch -> XCD affinity (grid.x == 8)
    const int q0   = blockIdx.y * 16;
    const int hg   = blockIdx.z;      // head-group 0/1 (8 heads each)

    const int row16 = quad * 4;

    f32x4 wacc[16] = {};
    f32x4 s[16];
    float mw[4], sw[4];

    // ---- prologue: QK for head hg*8 + softmax phase (not overlapped) ----
    {
        const int dbase = (hg * 8) * HDV + quad * 8;
        const u16* qp = q + (size_t)(b * LQV + q0 + r) * DIMV + dbase;
        const bfrag qa0 = *reinterpret_cast<const bfrag*>(qp);
        const bfrag qa1 = *reinterpret_cast<const bfrag*>(qp + 32);
#pragma unroll
        for (int u = 0; u < 16; ++u) {
            const u16* kp = k + (size_t)(b * LKV + w * 256 + u * 16 + r) * DIMV + dbase;
            const bfrag kb0 = *reinterpret_cast<const bfrag*>(kp);
            const bfrag kb1 = *reinterpret_cast<const bfrag*>(kp + 32);
            f32x4 a = {};
            a    = __builtin_amdgcn_mfma_f32_16x16x32_bf16(qa0, kb0, a, 0, 0, 0);
            s[u] = __builtin_amdgcn_mfma_f32_16x16x32_bf16(qa1, kb1, a, 0, 0, 0);
        }
        sm_reduce(s, mw, sw);
    }

    for (int hh = 0; hh < 8; ++hh) {
        const int h = hg * 8 + hh;

        if (r == 0) {
#pragma unroll
            for (int reg = 0; reg < 4; ++reg) {
                redm[w * 16 + row16 + reg] = mw[reg];
                reds[w * 16 + row16 + reg] = sw[reg];
            }
        }
        __syncthreads();   // bar A: redm/reds ready; also: all PV(h-1) sP reads done

        // ---- flash combine: factor = exp(m_w - M) / total ----
        float factor[4];
#pragma unroll
        for (int reg = 0; reg < 4; ++reg) {
            const int rr = row16 + reg;
            const float m0 = redm[rr], m1 = redm[16 + rr], m2 = redm[32 + rr], m3 = redm[48 + rr];
            const float M = fmaxf(fmaxf(m0, m1), fmaxf(m2, m3));
            const float total = __expf(m0 - M) * reds[rr]      + __expf(m1 - M) * reds[16 + rr] +
                                __expf(m2 - M) * reds[32 + rr] + __expf(m3 - M) * reds[48 + rr];
            factor[reg] = __expf(mw[reg] - M) / total;
        }

        // ---- normalize, accumulate mean-prob, write bf16 P to LDS ----
#pragma unroll
        for (int i = 0; i < 16; ++i)
#pragma unroll
            for (int reg = 0; reg < 4; ++reg) {
                const float pn = s[i][reg] * factor[reg];
                wacc[i][reg] += pn;
                sP[(row16 + reg) * PSTR + w * 256 + i * 16 + r] = f2bf(pn);
            }
        __syncthreads();   // bar B: sP(h) ready for PV

        // ---- overlap region: PV(h) interleaved with QK(h+1) ----
        const int n0 = w * 16;
        const u16* vb = vT + (size_t)(b * DIMV + h * HDV + n0 + r) * LKV;
        f32x4 c0 = {}, c1 = {}, c2 = {}, c3 = {};

        if (hh < 7) {
            const int dbase2 = (h + 1) * HDV + quad * 8;
            const u16* qp2 = q + (size_t)(b * LQV + q0 + r) * DIMV + dbase2;
            const bfrag qa0 = *reinterpret_cast<const bfrag*>(qp2);
            const bfrag qa1 = *reinterpret_cast<const bfrag*>(qp2 + 32);
#pragma unroll
            for (int u = 0; u < 16; ++u) {
                // QK iter u for head h+1 (global K + MFMA, s[] regs are dead -> reuse)
                const u16* kp = k + (size_t)(b * LKV + w * 256 + u * 16 + r) * DIMV + dbase2;
                const bfrag kb0 = *reinterpret_cast<const bfrag*>(kp);
                const bfrag kb1 = *reinterpret_cast<const bfrag*>(kp + 32);
                f32x4 a = {};
                a    = __builtin_amdgcn_mfma_f32_16x16x32_bf16(qa0, kb0, a, 0, 0, 0);
                s[u] = __builtin_amdgcn_mfma_f32_16x16x32_bf16(qa1, kb1, a, 0, 0, 0);
                // PV iter u (first 8): LDS P + global V, 4 independent chains
                if (u < 8) {
                    const int kk = u * 128;
                    const bfrag a0 = *reinterpret_cast<const bfrag*>(&sP[r * PSTR + kk      + quad * 8]);
                    const bfrag a1 = *reinterpret_cast<const bfrag*>(&sP[r * PSTR + kk + 32 + quad * 8]);
                    const bfrag a2 = *reinterpret_cast<const bfrag*>(&sP[r * PSTR + kk + 64 + quad * 8]);
                    const bfrag a3 = *reinterpret_cast<const bfrag*>(&sP[r * PSTR + kk + 96 + quad * 8]);
                    const bfrag b0 = *reinterpret_cast<const bfrag*>(vb + kk      + quad * 8);
                    const bfrag b1 = *reinterpret_cast<const bfrag*>(vb + kk + 32 + quad * 8);
                    const bfrag b2 = *reinterpret_cast<const bfrag*>(vb + kk + 64 + quad * 8);
                    const bfrag b3 = *reinterpret_cast<const bfrag*>(vb + kk + 96 + quad * 8);
                    c0 = __builtin_amdgcn_mfma_f32_16x16x32_bf16(a0, b0, c0, 0, 0, 0);
                    c1 = __builtin_amdgcn_mfma_f32_16x16x32_bf16(a1, b1, c1, 0, 0, 0);
                    c2 = __builtin_amdgcn_mfma_f32_16x16x32_bf16(a2, b2, c2, 0, 0, 0);
                    c3 = __builtin_amdgcn_mfma_f32_16x16x32_bf16(a3, b3, c3, 0, 0, 0);
                }
            }
            sm_reduce(s, mw, sw);   // softmax phase for head h+1 (reg/shuffle only)
        } else {
            // last head: PV only
#pragma unroll
            for (int u = 0; u < 8; ++u) {
                const int kk = u * 128;
                const bfrag a0 = *reinterpret_cast<const bfrag*>(&sP[r * PSTR + kk      + quad * 8]);
                const bfrag a1 = *reinterpret_cast<const bfrag*>(&sP[r * PSTR + kk + 32 + quad * 8]);
                const bfrag a2 = *reinterpret_cast<const bfrag*>(&sP[r * PSTR + kk + 64 + quad * 8]);
                const bfrag a3 = *reinterpret_cast<const bfrag*>(&sP[r * PSTR + kk + 96 + quad * 8]);
                const bfrag b0 = *reinterpret_cast<const bfrag*>(vb + kk      + quad * 8);
                const bfrag b1 = *reinterpret_cast<const bfrag*>(vb + kk + 32 + quad * 8);
                const bfrag b2 = *reinterpret_cast<const bfrag*>(vb + kk + 64 + quad * 8);
                const bfrag b3 = *reinterpret_cast<const bfrag*>(vb + kk + 96 + quad * 8);
                c0 = __builtin_amdgcn_mfma_f32_16x16x32_bf16(a0, b0, c0, 0, 0, 0);
                c1 = __builtin_amdgcn_mfma_f32_16x16x32_bf16(a1, b1, c1, 0, 0, 0);
                c2 = __builtin_amdgcn_mfma_f32_16x16x32_bf16(a2, b2, c2, 0, 0, 0);
                c3 = __builtin_amdgcn_mfma_f32_16x16x32_bf16(a3, b3, c3, 0, 0, 0);
            }
        }

        const f32x4 c = (c0 + c1) + (c2 + c3);
#pragma unroll
        for (int reg = 0; reg < 4; ++reg)
            ctx[(size_t)(b * LQV + q0 + row16 + reg) * DIMV + h * HDV + n0 + r] = f2bf(c[reg]);
    }

    // ---- attn_weights mean: this block's 8-head sum; 2-way atomic combine ----
    const float inv16 = 1.0f / 16.0f;
#pragma unroll
    for (int i = 0; i < 16; ++i)
#pragma unroll
        for (int reg = 0; reg < 4; ++reg)
            atomicAdd(&attnw[(size_t)(b * LQV + q0 + row16 + reg) * LKV + w * 256 + i * 16 + r],
                      wacc[i][reg] * inv16);
}

// LayerNorm per row of 1024; x fp32 (attended+residual), g/b fp32, out fp32
__global__ __launch_bounds__(256)
void ln_kernel(const float* __restrict__ x, const float* __restrict__ g,
               const float* __restrict__ bta, float* __restrict__ out)
{
    __shared__ float red[8];
    const int row = blockIdx.x;
    const int t = threadIdx.x;
    const int w = t >> 6;
    const float4 xv = reinterpret_cast<const float4*>(x + (size_t)row * DIMV)[t];

    float s = xv.x + xv.y + xv.z + xv.w;
#pragma unroll
    for (int off = 32; off; off >>= 1) s += __shfl_down(s, off);
    if ((t & 63) == 0) red[w] = s;
    __syncthreads();
    const float mu = (red[0] + red[1] + red[2] + red[3]) * (1.0f / 1024.0f);

    const float d0 = xv.x - mu, d1 = xv.y - mu, d2 = xv.z - mu, d3 = xv.w - mu;
    float s2 = d0 * d0 + d1 * d1 + d2 * d2 + d3 * d3;
#pragma unroll
    for (int off = 32; off; off >>= 1) s2 += __shfl_down(s2, off);
    if ((t & 63) == 0) red[4 + w] = s2;
    __syncthreads();
    const float var = (red[4] + red[5] + red[6] + red[7]) * (1.0f / 1024.0f);
    const float inv = rsqrtf(var + 1e-5f);

    float4 o;
    const int c = t * 4;
    o.x = d0 * inv * g[c + 0] + bta[c + 0];
    o.y = d1 * inv * g[c + 1] + bta[c + 1];
    o.z = d2 * inv * g[c + 2] + bta[c + 2];
    o.w = d3 * inv * g[c + 3] + bta[c + 3];
    reinterpret_cast<float4*>(out + (size_t)row * DIMV)[t] = o;
}

extern "C" void kernel_launch(void* const* d_in, const int* in_sizes, int n_in,
                              void* d_out, int out_size, void* d_ws, size_t ws_size,
                              hipStream_t stream)
{
    const float* text = (const float*)d_in[0];   // (8,512,1024)
    const float* vis  = (const float*)d_in[1];   // (8,1024,1024)
    const float* wqkv = (const float*)d_in[2];   // (3072,1024)
    const float* bqkv = (const float*)d_in[3];   // (3072,)
    const float* outw = (const float*)d_in[4];   // (1024,1024)
    const float* outb = (const float*)d_in[5];   // (1024,)
    const float* lng  = (const float*)d_in[6];   // (1024,)
    const float* lnb  = (const float*)d_in[7];   // (1024,)

    // Workspace overlays (64 MiB). text_bf relocated into d_out's out-region
    // (dead until ln_kernel) so kb no longer aliases it -> QKV fusable.
    char* ws = (char*)d_ws;
    u16*   vis_bf  = (u16*)(ws);                          // 0-16M
    u16*   ctxb    = (u16*)(ws);                          // 0-8M   (attn w; gemm_out r)
    u16*   wqkv_bf = (u16*)(ws + (size_t)(16u << 20));    // 16-22M
    u16*   outw_bf = (u16*)(ws + (size_t)(22u << 20));    // 22-24M
    u16*   qb      = (u16*)(ws + (size_t)(24u << 20));    // 24-32M
    u16*   kb      = (u16*)(ws + (size_t)(32u << 20));    // 32-48M
    float* attb    = (float*)(ws + (size_t)(32u << 20));  // 32-48M (gemm_out w; ln r)
    u16*   vTb     = (u16*)(ws + (size_t)(48u << 20));    // 48-64M

    float* outp  = (float*)d_out;                 // fp32 outputs, concat (out, attn_weights)
    float* attnw = outp + (size_t)4096 * 1024;
    u16*   text_bf = (u16*)outp;                  // 8MB scratch in out-region (rewritten by ln)

    const dim3 blk(256);
    // stage 0: all casts, one dispatch
    cast_all<<<dim3(16384), blk, 0, stream>>>(vis, wqkv, outw, text,
                                              vis_bf, wqkv_bf, outw_bf, text_bf);
    // stage 1: Q,K,V^T projections, one dispatch (1280 blocks)
    qkv_gemm<<<dim3(160, 8), blk, 0, stream>>>(text_bf, vis_bf, wqkv_bf, bqkv, qb, kb, vTb);
    // stage 2: attention; 512 blocks (2/CU), no register cap, 2-way atomic attnw
    hipMemsetAsync(attnw, 0, (size_t)4096 * 1024 * sizeof(float), stream);
    attn_kernel<<<dim3(8, 32, 2), blk, 0, stream>>>(qb, kb, vTb, ctxb, attnw);
    // stage 3: attended = ctx @ out_w^T + out_b + text (fp32), over dead kb
    gemm_out<<<dim3(32, 8), blk, 0, stream>>>(ctxb, outw_bf, outb, attb, text);
    // stage 4: layernorm -> out (fp32)
    ln_kernel<<<dim3(4096), blk, 0, stream>>>(attb, lng, lnb, outp);
}

// Round 8
// 411.556 us; speedup vs baseline: 1.1821x; 1.1032x over previous
//
#include <hip/hip_runtime.h>

#define DIMV 1024
#define NHV  16
#define HDV  64
#define BV   8
#define LQV  512
#define LKV  1024
#define PSTR 1032   // sP row stride in bf16: 2064B/row -> 2-way banks max (free)

typedef __bf16 bfrag  __attribute__((ext_vector_type(8)));
typedef float  f32x4  __attribute__((ext_vector_type(4)));
typedef unsigned short u16;
typedef unsigned int   u32;
typedef unsigned long long u64;

typedef const __attribute__((address_space(1))) u32 gu32;
typedef __attribute__((address_space(3))) u32 lu32;

__device__ __forceinline__ u16 f2bf(float f) {
    u32 x = __builtin_bit_cast(u32, f);
    x = x + 0x7FFFu + ((x >> 16) & 1u);   // RNE
    return (u16)(x >> 16);
}

// async global->LDS, 16B per lane; LDS dest must be wave-uniform base (+lane*16 implicit)
__device__ __forceinline__ void g2l16(const u16* g, const u16* l) {
    __builtin_amdgcn_global_load_lds(
        reinterpret_cast<gu32*>(reinterpret_cast<u64>(g)),
        reinterpret_cast<lu32*>((u32)reinterpret_cast<u64>(l)),
        16, 0, 0);
}

// All four fp32->bf16 casts in ONE dispatch (ranges exact multiples, no bounds checks)
__global__ __launch_bounds__(256)
void cast_all(const float* __restrict__ vis,  const float* __restrict__ wqkv,
              const float* __restrict__ outw, const float* __restrict__ text,
              u16* __restrict__ vis_bf, u16* __restrict__ wqkv_bf,
              u16* __restrict__ outw_bf, u16* __restrict__ text_bf)
{
    const int bx = blockIdx.x;
    const float* src; u16* dst; int i;
    if (bx < 8192)       { src = vis;  dst = vis_bf;  i = bx * 256 + threadIdx.x; }
    else if (bx < 11264) { src = wqkv; dst = wqkv_bf; i = (bx - 8192) * 256 + threadIdx.x; }
    else if (bx < 12288) { src = outw; dst = outw_bf; i = (bx - 11264) * 256 + threadIdx.x; }
    else                 { src = text; dst = text_bf; i = (bx - 12288) * 256 + threadIdx.x; }
    const float4 v = reinterpret_cast<const float4*>(src)[i];
    ushort4 o;
    o.x = f2bf(v.x); o.y = f2bf(v.y); o.z = f2bf(v.z); o.w = f2bf(v.w);
    reinterpret_cast<ushort4*>(dst)[i] = o;
}

// Q+K+V projections in ONE dispatch: grid.x = 32(Q) + 64(K) + 64(V^T) row-tiles,
// grid.y = 8 col-tiles. 1280 blocks -> ~5 blocks/CU vs 3 serialized underfilled
// launches. Body identical to m97-style gemm_nt; per-block uniform operand select.
__global__ __launch_bounds__(256)
void qkv_gemm(const u16* __restrict__ text_bf, const u16* __restrict__ vis_bf,
              const u16* __restrict__ wqkv_bf, const float* __restrict__ bqkv,
              u16* __restrict__ qb, u16* __restrict__ kb, u16* __restrict__ vTb)
{
    __shared__ __align__(16) u16 sA[128 * 64];
    __shared__ __align__(16) u16 sB[128 * 64];

    const int bx = blockIdx.x;
    const u16* A; const u16* W; const float* bias; u16* C; int mb, vmode;
    if (bx < 32)      { A = text_bf; W = wqkv_bf;               bias = bqkv;        C = qb;  mb = bx * 128;        vmode = 0; }
    else if (bx < 96) { A = vis_bf;  W = wqkv_bf + 1024 * 1024; bias = bqkv + 1024; C = kb;  mb = (bx - 32) * 128; vmode = 0; }
    else              { A = vis_bf;  W = wqkv_bf + 2097152;     bias = bqkv + 2048; C = vTb; mb = (bx - 96) * 128; vmode = 1; }

    const int t    = threadIdx.x;
    const int lane = t & 63;
    const int w    = t >> 6;
    const int quad = lane >> 4;
    const int r    = lane & 15;
    const int wr   = (w >> 1) * 64;
    const int wc   = (w & 1) * 64;
    const int nb   = blockIdx.y * 128;

    const int srow  = lane >> 3;
    const int skoff = (lane & 7) * 8;

    f32x4 acc[4][4] = {};

    const u16* Abase = A + (size_t)mb * 1024 + skoff;
    const u16* Wbase = W + (size_t)nb * 1024 + skoff;

    for (int k0 = 0; k0 < 1024; k0 += 64) {
#pragma unroll
        for (int it = 0; it < 4; ++it) {
            const int c = w * 4 + it;
            const int row = c * 8 + srow;
            g2l16(Abase + (size_t)row * 1024 + k0, sA + c * 512);
            g2l16(Wbase + (size_t)row * 1024 + k0, sB + c * 512);
        }
        __syncthreads();
#pragma unroll
        for (int kk = 0; kk < 2; ++kk) {
            bfrag af[4], bg[4];
#pragma unroll
            for (int i = 0; i < 4; ++i)
                af[i] = *reinterpret_cast<const bfrag*>(sA + (wr + i * 16 + r) * 64 + kk * 32 + quad * 8);
#pragma unroll
            for (int j = 0; j < 4; ++j)
                bg[j] = *reinterpret_cast<const bfrag*>(sB + (wc + j * 16 + r) * 64 + kk * 32 + quad * 8);
#pragma unroll
            for (int i = 0; i < 4; ++i)
#pragma unroll
                for (int j = 0; j < 4; ++j)
                    acc[i][j] = __builtin_amdgcn_mfma_f32_16x16x32_bf16(af[i], bg[j], acc[i][j], 0, 0, 0);
        }
        __syncthreads();
    }

#pragma unroll
    for (int i = 0; i < 4; i++)
#pragma unroll
    for (int j = 0; j < 4; j++) {
        const int colg = nb + wc + j * 16 + r;
        const float bv = bias[colg];
#pragma unroll
        for (int reg = 0; reg < 4; reg++) {
            const int rowg = mb + wr + i * 16 + quad * 4 + reg;
            const float v = acc[i][j][reg] + bv;
            if (vmode == 0) {
                C[(size_t)rowg * 1024 + colg] = f2bf(v);
            } else {
                C[((size_t)((rowg >> 10) << 10) + colg) * 1024 + (rowg & 1023)] = f2bf(v);
            }
        }
    }
}

// Stage-5 GEMM: attended = ctx @ out_w^T + out_b + text (fp32 out with residual)
__global__ __launch_bounds__(256)
void gemm_out(const u16* __restrict__ A, const u16* __restrict__ W,
              const float* __restrict__ bias, float* __restrict__ Cout,
              const float* __restrict__ resid)
{
    __shared__ __align__(16) u16 sA[128 * 64];
    __shared__ __align__(16) u16 sB[128 * 64];

    const int t    = threadIdx.x;
    const int lane = t & 63;
    const int w    = t >> 6;
    const int quad = lane >> 4;
    const int r    = lane & 15;
    const int wr   = (w >> 1) * 64;
    const int wc   = (w & 1) * 64;
    const int mb   = blockIdx.x * 128;
    const int nb   = blockIdx.y * 128;

    const int srow  = lane >> 3;
    const int skoff = (lane & 7) * 8;

    f32x4 acc[4][4] = {};

    const u16* Abase = A + (size_t)mb * 1024 + skoff;
    const u16* Wbase = W + (size_t)nb * 1024 + skoff;

    for (int k0 = 0; k0 < 1024; k0 += 64) {
#pragma unroll
        for (int it = 0; it < 4; ++it) {
            const int c = w * 4 + it;
            const int row = c * 8 + srow;
            g2l16(Abase + (size_t)row * 1024 + k0, sA + c * 512);
            g2l16(Wbase + (size_t)row * 1024 + k0, sB + c * 512);
        }
        __syncthreads();
#pragma unroll
        for (int kk = 0; kk < 2; ++kk) {
            bfrag af[4], bg[4];
#pragma unroll
            for (int i = 0; i < 4; ++i)
                af[i] = *reinterpret_cast<const bfrag*>(sA + (wr + i * 16 + r) * 64 + kk * 32 + quad * 8);
#pragma unroll
            for (int j = 0; j < 4; ++j)
                bg[j] = *reinterpret_cast<const bfrag*>(sB + (wc + j * 16 + r) * 64 + kk * 32 + quad * 8);
#pragma unroll
            for (int i = 0; i < 4; ++i)
#pragma unroll
                for (int j = 0; j < 4; ++j)
                    acc[i][j] = __builtin_amdgcn_mfma_f32_16x16x32_bf16(af[i], bg[j], acc[i][j], 0, 0, 0);
        }
        __syncthreads();
    }

#pragma unroll
    for (int i = 0; i < 4; i++)
#pragma unroll
    for (int j = 0; j < 4; j++) {
        const int colg = nb + wc + j * 16 + r;
        const float bv = bias[colg];
#pragma unroll
        for (int reg = 0; reg < 4; reg++) {
            const int rowg = mb + wr + i * 16 + quad * 4 + reg;
            const float v = acc[i][j][reg] + bv;
            Cout[(size_t)rowg * 1024 + colg] = v + resid[(size_t)rowg * 1024 + colg];
        }
    }
}

// Attention v10 = v4 body (proven 157us, exactly 128 VGPR, zero spill) with the
// grid-limit removed. VGPR quantum model (r5/r7): HW rounds wave VGPR alloc to
// {64,128,256}; 128 -> 4 waves/SIMD allowed; v4 was capped at 8 waves/CU only
// because grid==256 blocks==1 block/CU. v10: z-split heads (8/block: 2 groups
// x 4 serial) -> 512 blocks -> 2 blocks/CU = 16 waves/CU. LDS 2x67KB=134KB
// <= 160KB. b-major grid.x: all blocks of batch b on XCD b (K/V L2-resident,
// FETCH 135->20.6MB mechanism from r5/r7). attnw: in-block LDS combine of 2
// groups + 2-way atomicAdd across z.
__global__ __launch_bounds__(512, 2)
void attn_kernel(const u16* __restrict__ q, const u16* __restrict__ k,
                 const u16* __restrict__ vT, u16* __restrict__ ctx,
                 float* __restrict__ attnw)
{
    __shared__ __align__(16) u16 sP[2][16 * PSTR];   // 66048 B (>= 64KB combine buf)
    __shared__ float redm[2][64];
    __shared__ float reds[2][64];

    const int t    = threadIdx.x;     // 0..511
    const int g    = t >> 8;          // group 0/1 (4 heads each)
    const int tg   = t & 255;         // thread within group
    const int lane = tg & 63;
    const int w    = tg >> 6;         // wave 0..3 within group
    const int quad = lane >> 4;       // 0..3
    const int r    = lane & 15;
    const int b    = blockIdx.x;      // batch -> XCD affinity (grid.x == 8)
    const int q0   = blockIdx.y * 16;
    const int z    = blockIdx.z;      // head-half 0/1

    const int row16 = quad * 4;
    const float scale = 0.125f;       // 1/sqrt(64)

    f32x4 wacc[16] = {};

    for (int hh = 0; hh < 4; ++hh) {
        const int h = z * 8 + g * 4 + hh;
        const int dbase = h * HDV + quad * 8;

        const u16* qp = q + (size_t)(b * LQV + q0 + r) * DIMV + dbase;
        const bfrag qa0 = *reinterpret_cast<const bfrag*>(qp);
        const bfrag qa1 = *reinterpret_cast<const bfrag*>(qp + 32);

        // ---- QK: wave w covers cols [256w,256w+256), scores in regs ----
        f32x4 s[16];
#pragma unroll
        for (int i = 0; i < 16; ++i) {
            const int n0 = w * 256 + i * 16;
            const u16* kp = k + (size_t)(b * LKV + n0 + r) * DIMV + dbase;
            const bfrag kb0 = *reinterpret_cast<const bfrag*>(kp);
            const bfrag kb1 = *reinterpret_cast<const bfrag*>(kp + 32);
            f32x4 a = {};
            a    = __builtin_amdgcn_mfma_f32_16x16x32_bf16(qa0, kb0, a, 0, 0, 0);
            s[i] = __builtin_amdgcn_mfma_f32_16x16x32_bf16(qa1, kb1, a, 0, 0, 0);
        }

        // ---- wave-local max over 256 cols per row ----
        float mw[4] = {-1e30f, -1e30f, -1e30f, -1e30f};
#pragma unroll
        for (int i = 0; i < 16; ++i)
#pragma unroll
            for (int reg = 0; reg < 4; ++reg) {
                s[i][reg] *= scale;
                mw[reg] = fmaxf(mw[reg], s[i][reg]);
            }
#pragma unroll
        for (int reg = 0; reg < 4; ++reg)
#pragma unroll
            for (int off = 1; off < 16; off <<= 1)
                mw[reg] = fmaxf(mw[reg], __shfl_xor(mw[reg], off));

        // ---- exp(s - m_w) + wave-local sum ----
        float sw[4] = {0.f, 0.f, 0.f, 0.f};
#pragma unroll
        for (int i = 0; i < 16; ++i)
#pragma unroll
            for (int reg = 0; reg < 4; ++reg) {
                s[i][reg] = __expf(s[i][reg] - mw[reg]);
                sw[reg] += s[i][reg];
            }
#pragma unroll
        for (int reg = 0; reg < 4; ++reg)
#pragma unroll
            for (int off = 1; off < 16; off <<= 1)
                sw[reg] += __shfl_xor(sw[reg], off);

        if (r == 0) {
#pragma unroll
            for (int reg = 0; reg < 4; ++reg) {
                redm[g][w * 16 + row16 + reg] = mw[reg];
                reds[g][w * 16 + row16 + reg] = sw[reg];
            }
        }
        __syncthreads();   // combine barrier

        // ---- flash combine: factor = exp(m_w - M) / total ----
        float factor[4];
#pragma unroll
        for (int reg = 0; reg < 4; ++reg) {
            const int rr = row16 + reg;
            const float m0 = redm[g][rr], m1 = redm[g][16 + rr], m2 = redm[g][32 + rr], m3 = redm[g][48 + rr];
            const float M = fmaxf(fmaxf(m0, m1), fmaxf(m2, m3));
            const float total = __expf(m0 - M) * reds[g][rr]      + __expf(m1 - M) * reds[g][16 + rr] +
                                __expf(m2 - M) * reds[g][32 + rr] + __expf(m3 - M) * reds[g][48 + rr];
            factor[reg] = __expf(mw[reg] - M) / total;
        }

        // ---- normalize, accumulate mean-prob, write bf16 P to LDS ----
#pragma unroll
        for (int i = 0; i < 16; ++i)
#pragma unroll
            for (int reg = 0; reg < 4; ++reg) {
                const float pn = s[i][reg] * factor[reg];
                wacc[i][reg] += pn;
                sP[g][(row16 + reg) * PSTR + w * 256 + i * 16 + r] = f2bf(pn);
            }
        __syncthreads();   // sP(h) ready for PV

        // ---- PV: wave w owns hd cols [16w,16w+16); 4 independent chains ----
        {
            const int n0 = w * 16;
            f32x4 c0 = {}, c1 = {}, c2 = {}, c3 = {};
            const u16* vb = vT + (size_t)(b * DIMV + h * HDV + n0 + r) * LKV;
#pragma unroll
            for (int kk = 0; kk < LKV; kk += 128) {
                const bfrag a0 = *reinterpret_cast<const bfrag*>(&sP[g][r * PSTR + kk      + quad * 8]);
                const bfrag a1 = *reinterpret_cast<const bfrag*>(&sP[g][r * PSTR + kk + 32 + quad * 8]);
                const bfrag a2 = *reinterpret_cast<const bfrag*>(&sP[g][r * PSTR + kk + 64 + quad * 8]);
                const bfrag a3 = *reinterpret_cast<const bfrag*>(&sP[g][r * PSTR + kk + 96 + quad * 8]);
                const bfrag b0 = *reinterpret_cast<const bfrag*>(vb + kk      + quad * 8);
                const bfrag b1 = *reinterpret_cast<const bfrag*>(vb + kk + 32 + quad * 8);
                const bfrag b2 = *reinterpret_cast<const bfrag*>(vb + kk + 64 + quad * 8);
                const bfrag b3 = *reinterpret_cast<const bfrag*>(vb + kk + 96 + quad * 8);
                c0 = __builtin_amdgcn_mfma_f32_16x16x32_bf16(a0, b0, c0, 0, 0, 0);
                c1 = __builtin_amdgcn_mfma_f32_16x16x32_bf16(a1, b1, c1, 0, 0, 0);
                c2 = __builtin_amdgcn_mfma_f32_16x16x32_bf16(a2, b2, c2, 0, 0, 0);
                c3 = __builtin_amdgcn_mfma_f32_16x16x32_bf16(a3, b3, c3, 0, 0, 0);
            }
            const f32x4 c = (c0 + c1) + (c2 + c3);
#pragma unroll
            for (int reg = 0; reg < 4; ++reg)
                ctx[(size_t)(b * LQV + q0 + row16 + reg) * DIMV + h * HDV + n0 + r] = f2bf(c[reg]);
        }
        __syncthreads();   // sP/redm/reds safe for next head
    }

    // ---- attn_weights: group1 stages its 4-head sum via LDS; group0 adds,
    //      then ONE 2-way atomicAdd across the z-halves (attnw pre-zeroed) ----
    float* cb = reinterpret_cast<float*>(&sP[0][0]);
    if (g == 1) {
#pragma unroll
        for (int i = 0; i < 16; ++i)
#pragma unroll
            for (int reg = 0; reg < 4; ++reg)
                cb[(i * 4 + reg) * 256 + tg] = wacc[i][reg];
    }
    __syncthreads();
    if (g == 0) {
        const float inv16 = 1.0f / 16.0f;
#pragma unroll
        for (int i = 0; i < 16; ++i)
#pragma unroll
            for (int reg = 0; reg < 4; ++reg) {
                const float v = (wacc[i][reg] + cb[(i * 4 + reg) * 256 + tg]) * inv16;
                atomicAdd(&attnw[(size_t)(b * LQV + q0 + row16 + reg) * LKV + w * 256 + i * 16 + r], v);
            }
    }
}

// LayerNorm per row of 1024; x fp32 (attended+residual), g/b fp32, out fp32
__global__ __launch_bounds__(256)
void ln_kernel(const float* __restrict__ x, const float* __restrict__ g,
               const float* __restrict__ bta, float* __restrict__ out)
{
    __shared__ float red[8];
    const int row = blockIdx.x;
    const int t = threadIdx.x;
    const int w = t >> 6;
    const float4 xv = reinterpret_cast<const float4*>(x + (size_t)row * DIMV)[t];

    float s = xv.x + xv.y + xv.z + xv.w;
#pragma unroll
    for (int off = 32; off; off >>= 1) s += __shfl_down(s, off);
    if ((t & 63) == 0) red[w] = s;
    __syncthreads();
    const float mu = (red[0] + red[1] + red[2] + red[3]) * (1.0f / 1024.0f);

    const float d0 = xv.x - mu, d1 = xv.y - mu, d2 = xv.z - mu, d3 = xv.w - mu;
    float s2 = d0 * d0 + d1 * d1 + d2 * d2 + d3 * d3;
#pragma unroll
    for (int off = 32; off; off >>= 1) s2 += __shfl_down(s2, off);
    if ((t & 63) == 0) red[4 + w] = s2;
    __syncthreads();
    const float var = (red[4] + red[5] + red[6] + red[7]) * (1.0f / 1024.0f);
    const float inv = rsqrtf(var + 1e-5f);

    float4 o;
    const int c = t * 4;
    o.x = d0 * inv * g[c + 0] + bta[c + 0];
    o.y = d1 * inv * g[c + 1] + bta[c + 1];
    o.z = d2 * inv * g[c + 2] + bta[c + 2];
    o.w = d3 * inv * g[c + 3] + bta[c + 3];
    reinterpret_cast<float4*>(out + (size_t)row * DIMV)[t] = o;
}

extern "C" void kernel_launch(void* const* d_in, const int* in_sizes, int n_in,
                              void* d_out, int out_size, void* d_ws, size_t ws_size,
                              hipStream_t stream)
{
    const float* text = (const float*)d_in[0];   // (8,512,1024)
    const float* vis  = (const float*)d_in[1];   // (8,1024,1024)
    const float* wqkv = (const float*)d_in[2];   // (3072,1024)
    const float* bqkv = (const float*)d_in[3];   // (3072,)
    const float* outw = (const float*)d_in[4];   // (1024,1024)
    const float* outb = (const float*)d_in[5];   // (1024,)
    const float* lng  = (const float*)d_in[6];   // (1024,)
    const float* lnb  = (const float*)d_in[7];   // (1024,)

    // Workspace overlays (64 MiB). text_bf relocated into d_out's out-region
    // (dead until ln_kernel) so kb no longer aliases it -> QKV fusable.
    char* ws = (char*)d_ws;
    u16*   vis_bf  = (u16*)(ws);                          // 0-16M
    u16*   ctxb    = (u16*)(ws);                          // 0-8M   (attn w; gemm_out r)
    u16*   wqkv_bf = (u16*)(ws + (size_t)(16u << 20));    // 16-22M
    u16*   outw_bf = (u16*)(ws + (size_t)(22u << 20));    // 22-24M
    u16*   qb      = (u16*)(ws + (size_t)(24u << 20));    // 24-32M
    u16*   kb      = (u16*)(ws + (size_t)(32u << 20));    // 32-48M
    float* attb    = (float*)(ws + (size_t)(32u << 20));  // 32-48M (gemm_out w; ln r)
    u16*   vTb     = (u16*)(ws + (size_t)(48u << 20));    // 48-64M

    float* outp  = (float*)d_out;                 // fp32 outputs, concat (out, attn_weights)
    float* attnw = outp + (size_t)4096 * 1024;
    u16*   text_bf = (u16*)outp;                  // 8MB scratch in out-region (rewritten by ln)

    const dim3 blk(256);
    // stage -1: zero attnw (atomic 2-way combine target; disjoint from text_bf)
    hipMemsetAsync(attnw, 0, (size_t)4096 * 1024 * sizeof(float), stream);
    // stage 0: all casts, one dispatch
    cast_all<<<dim3(16384), blk, 0, stream>>>(vis, wqkv, outw, text,
                                              vis_bf, wqkv_bf, outw_bf, text_bf);
    // stage 1: Q,K,V^T projections, one dispatch (1280 blocks)
    qkv_gemm<<<dim3(160, 8), blk, 0, stream>>>(text_bf, vis_bf, wqkv_bf, bqkv, qb, kb, vTb);
    // stage 2: attention; v4 body, 512 blocks (2/CU, 16 waves/CU), b-major XCD affinity
    attn_kernel<<<dim3(8, 32, 2), dim3(512), 0, stream>>>(qb, kb, vTb, ctxb, attnw);
    // stage 3: attended = ctx @ out_w^T + out_b + text (fp32), over dead kb
    gemm_out<<<dim3(32, 8), blk, 0, stream>>>(ctxb, outw_bf, outb, attb, text);
    // stage 4: layernorm -> out (fp32)
    ln_kernel<<<dim3(4096), blk, 0, stream>>>(attb, lng, lnb, outp);
}

// Round 9
// 373.969 us; speedup vs baseline: 1.3009x; 1.1005x over previous
//
#include <hip/hip_runtime.h>

#define DIMV 1024
#define NHV  16
#define HDV  64
#define BV   8
#define LQV  512
#define LKV  1024
#define PSTR 1032   // sP row stride in bf16: 2064B/row -> 2-way banks max (free)

typedef __bf16 bfrag  __attribute__((ext_vector_type(8)));
typedef float  f32x4  __attribute__((ext_vector_type(4)));
typedef unsigned short u16;
typedef unsigned int   u32;
typedef unsigned long long u64;

typedef const __attribute__((address_space(1))) u32 gu32;
typedef __attribute__((address_space(3))) u32 lu32;

__device__ __forceinline__ u16 f2bf(float f) {
    u32 x = __builtin_bit_cast(u32, f);
    x = x + 0x7FFFu + ((x >> 16) & 1u);   // RNE
    return (u16)(x >> 16);
}

// async global->LDS, 16B per lane; LDS dest must be wave-uniform base (+lane*16 implicit)
__device__ __forceinline__ void g2l16(const u16* g, const u16* l) {
    __builtin_amdgcn_global_load_lds(
        reinterpret_cast<gu32*>(reinterpret_cast<u64>(g)),
        reinterpret_cast<lu32*>((u32)reinterpret_cast<u64>(l)),
        16, 0, 0);
}

// All four fp32->bf16 casts in ONE dispatch (ranges exact multiples, no bounds checks)
__global__ __launch_bounds__(256)
void cast_all(const float* __restrict__ vis,  const float* __restrict__ wqkv,
              const float* __restrict__ outw, const float* __restrict__ text,
              u16* __restrict__ vis_bf, u16* __restrict__ wqkv_bf,
              u16* __restrict__ outw_bf, u16* __restrict__ text_bf)
{
    const int bx = blockIdx.x;
    const float* src; u16* dst; int i;
    if (bx < 8192)       { src = vis;  dst = vis_bf;  i = bx * 256 + threadIdx.x; }
    else if (bx < 11264) { src = wqkv; dst = wqkv_bf; i = (bx - 8192) * 256 + threadIdx.x; }
    else if (bx < 12288) { src = outw; dst = outw_bf; i = (bx - 11264) * 256 + threadIdx.x; }
    else                 { src = text; dst = text_bf; i = (bx - 12288) * 256 + threadIdx.x; }
    const float4 v = reinterpret_cast<const float4*>(src)[i];
    ushort4 o;
    o.x = f2bf(v.x); o.y = f2bf(v.y); o.z = f2bf(v.z); o.w = f2bf(v.w);
    reinterpret_cast<ushort4*>(dst)[i] = o;
}

// Q+K+V projections in ONE dispatch: grid.x = 32(Q) + 64(K) + 64(V^T) row-tiles,
// grid.y = 8 col-tiles. m97-style body; per-block uniform operand select.
__global__ __launch_bounds__(256)
void qkv_gemm(const u16* __restrict__ text_bf, const u16* __restrict__ vis_bf,
              const u16* __restrict__ wqkv_bf, const float* __restrict__ bqkv,
              u16* __restrict__ qb, u16* __restrict__ kb, u16* __restrict__ vTb)
{
    __shared__ __align__(16) u16 sA[128 * 64];
    __shared__ __align__(16) u16 sB[128 * 64];

    const int bx = blockIdx.x;
    const u16* A; const u16* W; const float* bias; u16* C; int mb, vmode;
    if (bx < 32)      { A = text_bf; W = wqkv_bf;               bias = bqkv;        C = qb;  mb = bx * 128;        vmode = 0; }
    else if (bx < 96) { A = vis_bf;  W = wqkv_bf + 1024 * 1024; bias = bqkv + 1024; C = kb;  mb = (bx - 32) * 128; vmode = 0; }
    else              { A = vis_bf;  W = wqkv_bf + 2097152;     bias = bqkv + 2048; C = vTb; mb = (bx - 96) * 128; vmode = 1; }

    const int t    = threadIdx.x;
    const int lane = t & 63;
    const int w    = t >> 6;
    const int quad = lane >> 4;
    const int r    = lane & 15;
    const int wr   = (w >> 1) * 64;
    const int wc   = (w & 1) * 64;
    const int nb   = blockIdx.y * 128;

    const int srow  = lane >> 3;
    const int skoff = (lane & 7) * 8;

    f32x4 acc[4][4] = {};

    const u16* Abase = A + (size_t)mb * 1024 + skoff;
    const u16* Wbase = W + (size_t)nb * 1024 + skoff;

    for (int k0 = 0; k0 < 1024; k0 += 64) {
#pragma unroll
        for (int it = 0; it < 4; ++it) {
            const int c = w * 4 + it;
            const int row = c * 8 + srow;
            g2l16(Abase + (size_t)row * 1024 + k0, sA + c * 512);
            g2l16(Wbase + (size_t)row * 1024 + k0, sB + c * 512);
        }
        __syncthreads();
#pragma unroll
        for (int kk = 0; kk < 2; ++kk) {
            bfrag af[4], bg[4];
#pragma unroll
            for (int i = 0; i < 4; ++i)
                af[i] = *reinterpret_cast<const bfrag*>(sA + (wr + i * 16 + r) * 64 + kk * 32 + quad * 8);
#pragma unroll
            for (int j = 0; j < 4; ++j)
                bg[j] = *reinterpret_cast<const bfrag*>(sB + (wc + j * 16 + r) * 64 + kk * 32 + quad * 8);
#pragma unroll
            for (int i = 0; i < 4; ++i)
#pragma unroll
                for (int j = 0; j < 4; ++j)
                    acc[i][j] = __builtin_amdgcn_mfma_f32_16x16x32_bf16(af[i], bg[j], acc[i][j], 0, 0, 0);
        }
        __syncthreads();
    }

#pragma unroll
    for (int i = 0; i < 4; i++)
#pragma unroll
    for (int j = 0; j < 4; j++) {
        const int colg = nb + wc + j * 16 + r;
        const float bv = bias[colg];
#pragma unroll
        for (int reg = 0; reg < 4; reg++) {
            const int rowg = mb + wr + i * 16 + quad * 4 + reg;
            const float v = acc[i][j][reg] + bv;
            if (vmode == 0) {
                C[(size_t)rowg * 1024 + colg] = f2bf(v);
            } else {
                C[((size_t)((rowg >> 10) << 10) + colg) * 1024 + (rowg & 1023)] = f2bf(v);
            }
        }
    }
}

// Stage-5 GEMM: attended = ctx @ out_w^T + out_b + text (fp32 out with residual)
__global__ __launch_bounds__(256)
void gemm_out(const u16* __restrict__ A, const u16* __restrict__ W,
              const float* __restrict__ bias, float* __restrict__ Cout,
              const float* __restrict__ resid)
{
    __shared__ __align__(16) u16 sA[128 * 64];
    __shared__ __align__(16) u16 sB[128 * 64];

    const int t    = threadIdx.x;
    const int lane = t & 63;
    const int w    = t >> 6;
    const int quad = lane >> 4;
    const int r    = lane & 15;
    const int wr   = (w >> 1) * 64;
    const int wc   = (w & 1) * 64;
    const int mb   = blockIdx.x * 128;
    const int nb   = blockIdx.y * 128;

    const int srow  = lane >> 3;
    const int skoff = (lane & 7) * 8;

    f32x4 acc[4][4] = {};

    const u16* Abase = A + (size_t)mb * 1024 + skoff;
    const u16* Wbase = W + (size_t)nb * 1024 + skoff;

    for (int k0 = 0; k0 < 1024; k0 += 64) {
#pragma unroll
        for (int it = 0; it < 4; ++it) {
            const int c = w * 4 + it;
            const int row = c * 8 + srow;
            g2l16(Abase + (size_t)row * 1024 + k0, sA + c * 512);
            g2l16(Wbase + (size_t)row * 1024 + k0, sB + c * 512);
        }
        __syncthreads();
#pragma unroll
        for (int kk = 0; kk < 2; ++kk) {
            bfrag af[4], bg[4];
#pragma unroll
            for (int i = 0; i < 4; ++i)
                af[i] = *reinterpret_cast<const bfrag*>(sA + (wr + i * 16 + r) * 64 + kk * 32 + quad * 8);
#pragma unroll
            for (int j = 0; j < 4; ++j)
                bg[j] = *reinterpret_cast<const bfrag*>(sB + (wc + j * 16 + r) * 64 + kk * 32 + quad * 8);
#pragma unroll
            for (int i = 0; i < 4; ++i)
#pragma unroll
                for (int j = 0; j < 4; ++j)
                    acc[i][j] = __builtin_amdgcn_mfma_f32_16x16x32_bf16(af[i], bg[j], acc[i][j], 0, 0, 0);
        }
        __syncthreads();
    }

#pragma unroll
    for (int i = 0; i < 4; i++)
#pragma unroll
    for (int j = 0; j < 4; j++) {
        const int colg = nb + wc + j * 16 + r;
        const float bv = bias[colg];
#pragma unroll
        for (int reg = 0; reg < 4; reg++) {
            const int rowg = mb + wr + i * 16 + quad * 4 + reg;
            const float v = acc[i][j][reg] + bv;
            Cout[(size_t)rowg * 1024 + colg] = v + resid[(size_t)rowg * 1024 + colg];
        }
    }
}

// Attention v11: v4 shape (512 thr, 2 groups x 8 heads, 256 blocks) with the
// per-head critical path cut down:
//  - max-free softmax: |s/8| <= ~6 so exp() is f32-safe; removes the max
//    reduce AND the max->exp serialization (exp issues as QK MFMAs retire).
//  - deferred normalization: sP holds RAW exp; factor = 1/sum is wave-
//    independent, applied to ctx AFTER the PV MFMA (linear). P-write no
//    longer waits for the cross-wave combine.
//  - ONE barrier/head via parity-double-buffered sP/reds (134KB LDS; blocks
//    never co-resided anyway per r0-r8 evidence).
//  - no atomics, no memset (full head ownership; v4-style LDS combine).
// Grid (8 b, 32 q): b-major keeps XCD L2 affinity (FETCH 20MB, r5/r7/r8).
__global__ __launch_bounds__(512, 2)
void attn_kernel(const u16* __restrict__ q, const u16* __restrict__ k,
                 const u16* __restrict__ vT, u16* __restrict__ ctx,
                 float* __restrict__ attnw)
{
    __shared__ __align__(16) u16 sP[2][2][16 * PSTR];   // [group][parity], 132096 B
    __shared__ float reds[2][2][64];                     // [group][parity]

    const int t    = threadIdx.x;     // 0..511
    const int g    = t >> 8;          // head-group 0/1 (8 heads each)
    const int tg   = t & 255;         // thread within group
    const int lane = tg & 63;
    const int w    = tg >> 6;         // wave 0..3 within group
    const int quad = lane >> 4;       // 0..3
    const int r    = lane & 15;
    const int b    = blockIdx.x;      // batch -> XCD affinity (grid.x == 8)
    const int q0   = blockIdx.y * 16;

    const int row16 = quad * 4;
    const float scale = 0.125f;       // 1/sqrt(64); folded into exp arg

    f32x4 wacc[16] = {};

    for (int hh = 0; hh < 8; ++hh) {
        const int h = g * 8 + hh;
        const int p = hh & 1;         // sP/reds parity
        const int dbase = h * HDV + quad * 8;

        const u16* qp = q + (size_t)(b * LQV + q0 + r) * DIMV + dbase;
        const bfrag qa0 = *reinterpret_cast<const bfrag*>(qp);
        const bfrag qa1 = *reinterpret_cast<const bfrag*>(qp + 32);

        // ---- QK: wave w covers cols [256w,256w+256), scores in regs ----
        f32x4 s[16];
#pragma unroll
        for (int i = 0; i < 16; ++i) {
            const int n0 = w * 256 + i * 16;
            const u16* kp = k + (size_t)(b * LKV + n0 + r) * DIMV + dbase;
            const bfrag kb0 = *reinterpret_cast<const bfrag*>(kp);
            const bfrag kb1 = *reinterpret_cast<const bfrag*>(kp + 32);
            f32x4 a = {};
            a    = __builtin_amdgcn_mfma_f32_16x16x32_bf16(qa0, kb0, a, 0, 0, 0);
            s[i] = __builtin_amdgcn_mfma_f32_16x16x32_bf16(qa1, kb1, a, 0, 0, 0);
        }

        // ---- max-free: p = exp(s/8); wave-local sum ----
        float sw[4] = {0.f, 0.f, 0.f, 0.f};
#pragma unroll
        for (int i = 0; i < 16; ++i)
#pragma unroll
            for (int reg = 0; reg < 4; ++reg) {
                s[i][reg] = __expf(s[i][reg] * scale);
                sw[reg] += s[i][reg];
            }
#pragma unroll
        for (int reg = 0; reg < 4; ++reg)
#pragma unroll
            for (int off = 1; off < 16; off <<= 1)
                sw[reg] += __shfl_xor(sw[reg], off);

        if (r == 0) {
#pragma unroll
            for (int reg = 0; reg < 4; ++reg)
                reds[g][p][w * 16 + row16 + reg] = sw[reg];
        }

        // ---- write RAW P (bf16) — no combine needed before write ----
#pragma unroll
        for (int i = 0; i < 16; ++i)
#pragma unroll
            for (int reg = 0; reg < 4; ++reg)
                sP[g][p][(row16 + reg) * PSTR + w * 256 + i * 16 + r] = f2bf(s[i][reg]);

        __syncthreads();   // single barrier: reds+P(h) visible; also fences buf reuse

        // ---- factor = 1/total (wave-independent) ----
        float factor[4];
#pragma unroll
        for (int reg = 0; reg < 4; ++reg) {
            const int rr = row16 + reg;
            const float tot = reds[g][p][rr]      + reds[g][p][16 + rr] +
                              reds[g][p][32 + rr] + reds[g][p][48 + rr];
            factor[reg] = 1.0f / tot;
        }

        // ---- attn_weights accumulation (this wave's own raw chunk) ----
#pragma unroll
        for (int i = 0; i < 16; ++i)
#pragma unroll
            for (int reg = 0; reg < 4; ++reg)
                wacc[i][reg] += s[i][reg] * factor[reg];

        // ---- PV on raw P; normalize ctx after MFMA ----
        {
            const int n0 = w * 16;
            f32x4 c0 = {}, c1 = {}, c2 = {}, c3 = {};
            const u16* vb = vT + (size_t)(b * DIMV + h * HDV + n0 + r) * LKV;
            const u16* sPb = &sP[g][p][r * PSTR + quad * 8];
#pragma unroll
            for (int kk = 0; kk < LKV; kk += 128) {
                const bfrag a0 = *reinterpret_cast<const bfrag*>(sPb + kk);
                const bfrag a1 = *reinterpret_cast<const bfrag*>(sPb + kk + 32);
                const bfrag a2 = *reinterpret_cast<const bfrag*>(sPb + kk + 64);
                const bfrag a3 = *reinterpret_cast<const bfrag*>(sPb + kk + 96);
                const bfrag b0 = *reinterpret_cast<const bfrag*>(vb + kk      + quad * 8);
                const bfrag b1 = *reinterpret_cast<const bfrag*>(vb + kk + 32 + quad * 8);
                const bfrag b2 = *reinterpret_cast<const bfrag*>(vb + kk + 64 + quad * 8);
                const bfrag b3 = *reinterpret_cast<const bfrag*>(vb + kk + 96 + quad * 8);
                c0 = __builtin_amdgcn_mfma_f32_16x16x32_bf16(a0, b0, c0, 0, 0, 0);
                c1 = __builtin_amdgcn_mfma_f32_16x16x32_bf16(a1, b1, c1, 0, 0, 0);
                c2 = __builtin_amdgcn_mfma_f32_16x16x32_bf16(a2, b2, c2, 0, 0, 0);
                c3 = __builtin_amdgcn_mfma_f32_16x16x32_bf16(a3, b3, c3, 0, 0, 0);
            }
            const f32x4 c = (c0 + c1) + (c2 + c3);
#pragma unroll
            for (int reg = 0; reg < 4; ++reg)
                ctx[(size_t)(b * LQV + q0 + row16 + reg) * DIMV + h * HDV + n0 + r] =
                    f2bf(c[reg] * factor[reg]);
        }
        // NO trailing barrier: next head writes the other parity buffer; the
        // h+2 re-write of this parity happens after barrier(h+1), which this
        // wave only reaches after its PV(h) LDS reads retire.
    }

    __syncthreads();   // all PV reads done before cb staging

    // ---- attn_weights mean: group1 stages wacc via LDS; group0 adds + stores ----
    float* cb = reinterpret_cast<float*>(&sP[0][0][0]);
    if (g == 1) {
#pragma unroll
        for (int i = 0; i < 16; ++i)
#pragma unroll
            for (int reg = 0; reg < 4; ++reg)
                cb[(i * 4 + reg) * 256 + tg] = wacc[i][reg];
    }
    __syncthreads();
    if (g == 0) {
        const float inv16 = 1.0f / 16.0f;
#pragma unroll
        for (int i = 0; i < 16; ++i)
#pragma unroll
            for (int reg = 0; reg < 4; ++reg) {
                const float v = (wacc[i][reg] + cb[(i * 4 + reg) * 256 + tg]) * inv16;
                attnw[(size_t)(b * LQV + q0 + row16 + reg) * LKV + w * 256 + i * 16 + r] = v;
            }
    }
}

// LayerNorm per row of 1024; x fp32 (attended+residual), g/b fp32, out fp32
__global__ __launch_bounds__(256)
void ln_kernel(const float* __restrict__ x, const float* __restrict__ g,
               const float* __restrict__ bta, float* __restrict__ out)
{
    __shared__ float red[8];
    const int row = blockIdx.x;
    const int t = threadIdx.x;
    const int w = t >> 6;
    const float4 xv = reinterpret_cast<const float4*>(x + (size_t)row * DIMV)[t];

    float s = xv.x + xv.y + xv.z + xv.w;
#pragma unroll
    for (int off = 32; off; off >>= 1) s += __shfl_down(s, off);
    if ((t & 63) == 0) red[w] = s;
    __syncthreads();
    const float mu = (red[0] + red[1] + red[2] + red[3]) * (1.0f / 1024.0f);

    const float d0 = xv.x - mu, d1 = xv.y - mu, d2 = xv.z - mu, d3 = xv.w - mu;
    float s2 = d0 * d0 + d1 * d1 + d2 * d2 + d3 * d3;
#pragma unroll
    for (int off = 32; off; off >>= 1) s2 += __shfl_down(s2, off);
    if ((t & 63) == 0) red[4 + w] = s2;
    __syncthreads();
    const float var = (red[4] + red[5] + red[6] + red[7]) * (1.0f / 1024.0f);
    const float inv = rsqrtf(var + 1e-5f);

    float4 o;
    const int c = t * 4;
    o.x = d0 * inv * g[c + 0] + bta[c + 0];
    o.y = d1 * inv * g[c + 1] + bta[c + 1];
    o.z = d2 * inv * g[c + 2] + bta[c + 2];
    o.w = d3 * inv * g[c + 3] + bta[c + 3];
    reinterpret_cast<float4*>(out + (size_t)row * DIMV)[t] = o;
}

extern "C" void kernel_launch(void* const* d_in, const int* in_sizes, int n_in,
                              void* d_out, int out_size, void* d_ws, size_t ws_size,
                              hipStream_t stream)
{
    const float* text = (const float*)d_in[0];   // (8,512,1024)
    const float* vis  = (const float*)d_in[1];   // (8,1024,1024)
    const float* wqkv = (const float*)d_in[2];   // (3072,1024)
    const float* bqkv = (const float*)d_in[3];   // (3072,)
    const float* outw = (const float*)d_in[4];   // (1024,1024)
    const float* outb = (const float*)d_in[5];   // (1024,)
    const float* lng  = (const float*)d_in[6];   // (1024,)
    const float* lnb  = (const float*)d_in[7];   // (1024,)

    // Workspace overlays (64 MiB). text_bf lives in d_out's out-region
    // (dead until ln_kernel rewrites it) so kb doesn't alias it.
    char* ws = (char*)d_ws;
    u16*   vis_bf  = (u16*)(ws);                          // 0-16M
    u16*   ctxb    = (u16*)(ws);                          // 0-8M   (attn w; gemm_out r)
    u16*   wqkv_bf = (u16*)(ws + (size_t)(16u << 20));    // 16-22M
    u16*   outw_bf = (u16*)(ws + (size_t)(22u << 20));    // 22-24M
    u16*   qb      = (u16*)(ws + (size_t)(24u << 20));    // 24-32M
    u16*   kb      = (u16*)(ws + (size_t)(32u << 20));    // 32-48M
    float* attb    = (float*)(ws + (size_t)(32u << 20));  // 32-48M (gemm_out w; ln r)
    u16*   vTb     = (u16*)(ws + (size_t)(48u << 20));    // 48-64M

    float* outp  = (float*)d_out;                 // fp32 outputs, concat (out, attn_weights)
    float* attnw = outp + (size_t)4096 * 1024;
    u16*   text_bf = (u16*)outp;                  // 8MB scratch in out-region

    const dim3 blk(256);
    // stage 0: all casts, one dispatch
    cast_all<<<dim3(16384), blk, 0, stream>>>(vis, wqkv, outw, text,
                                              vis_bf, wqkv_bf, outw_bf, text_bf);
    // stage 1: Q,K,V^T projections, one dispatch (1280 blocks)
    qkv_gemm<<<dim3(160, 8), blk, 0, stream>>>(text_bf, vis_bf, wqkv_bf, bqkv, qb, kb, vTb);
    // stage 2: attention; 256 blocks, 1 barrier/head, max-free softmax, no atomics
    attn_kernel<<<dim3(8, 32), dim3(512), 0, stream>>>(qb, kb, vTb, ctxb, attnw);
    // stage 3: attended = ctx @ out_w^T + out_b + text (fp32), over dead kb
    gemm_out<<<dim3(32, 8), blk, 0, stream>>>(ctxb, outw_bf, outb, attb, text);
    // stage 4: layernorm -> out (fp32)
    ln_kernel<<<dim3(4096), blk, 0, stream>>>(attb, lng, lnb, outp);
}